// Round 4
// baseline (3321.363 us; speedup 1.0000x reference)
//
#include <hip/hip_runtime.h>
#include <math.h>

// Problem constants
#define B 128
#define T 256
#define D 512
#define H 1024
#define KTOT 1536   // D + H
#define N4 4096     // 4*H

// h ring: one slab per step, 4KB skew to break any L2 stream prefetch.
// Virgin addresses within the dispatch => cached consumer loads can never be
// stale (inter-dispatch L2 wb+inv is proven by xb working across XCDs).
#define HSTRIDE ((size_t)B * H + 2048)   // in ushorts; 266240 B per step

typedef short short8 __attribute__((ext_vector_type(8)));
typedef float f32x16 __attribute__((ext_vector_type(16)));

__device__ __forceinline__ unsigned short f2bf(float f) {
    unsigned int u = __builtin_bit_cast(unsigned int, f);
    unsigned int r = (u + 0x7fffu + ((u >> 16) & 1u)) >> 16;  // RNE
    return (unsigned short)r;
}
__device__ __forceinline__ float bf2f(unsigned short s) {
    unsigned int u = ((unsigned int)s) << 16;
    return __builtin_bit_cast(float, u);
}
__device__ __forceinline__ float sigm(float x) { return 1.f / (1.f + __expf(-x)); }
__device__ __forceinline__ float tanh_fast(float x) {
    return 1.f - 2.f / (1.f + __expf(2.f * x));
}

// x fp32 [B][T][D] -> xb bf16 [T][B][D]
__global__ __launch_bounds__(256) void convert_x(
    const float* __restrict__ x, unsigned short* __restrict__ xb)
{
    int bid = blockIdx.x;          // t*B + b
    int t = bid >> 7;
    int b = bid & 127;
    int d = threadIdx.x * 2;
    const float2 v = *(const float2*)&x[((size_t)b * T + t) * D + d];
    unsigned int packed = (unsigned int)f2bf(v.x) | ((unsigned int)f2bf(v.y) << 16);
    *(unsigned int*)&xb[((size_t)t * B + b) * D + d] = packed;
}

// Wk fp32 [KTOT][4H] -> Wp bf16 [4096][KTOT], permuted: pcol = hc*4 + g
__global__ __launch_bounds__(256) void convert_W(
    const float* __restrict__ Wk, unsigned short* __restrict__ Wp)
{
    __shared__ float tile[32][33];
    int nb = blockIdx.x;   // 0..127
    int kb = blockIdx.y;   // 0..47
    int tx = threadIdx.x & 31;
    int ty = threadIdx.x >> 5;   // 0..7
    #pragma unroll
    for (int i = 0; i < 4; ++i) {
        int k = kb * 32 + ty + i * 8;
        tile[ty + i * 8][tx] = Wk[(size_t)k * N4 + nb * 32 + tx];
    }
    __syncthreads();
    #pragma unroll
    for (int i = 0; i < 4; ++i) {
        int n = nb * 32 + ty + i * 8;
        int pcol = ((n & 1023) << 2) | (n >> 10);
        Wp[(size_t)pcol * KTOT + kb * 32 + tx] = f2bf(tile[tx][ty + i * 8]);
    }
}

// Persistent LSTM. 256 blocks x 256 threads, 1 block/CU, W in registers.
// Wave w = K-quarter kq. One barrier/step (zbuf double-buffered); gates store
// their own packed uint directly (no hbuf stage); pipelined hot poll; x-MFMAs
// execute under the h cache-fill shadow. rg clustered 2 XCDs (bi&7 pairing).
__global__ __launch_bounds__(256, 1) void lstm_persist(
    const unsigned short* __restrict__ xb,     // [T][B][D] bf16
    const unsigned short* __restrict__ Wp,     // [4096][KTOT] bf16 permuted
    const float* __restrict__ bk,              // [4H]
    unsigned short* __restrict__ hring,        // [T][HSTRIDE] bf16 ring
    unsigned int* __restrict__ arr)            // [4 rg][64 cg] block flags (zeroed)
{
    __shared__ float zbuf[2][4][64][36];           // dbuf K-quarter partials, 73728 B
    __shared__ unsigned int wcnt;                  // monotonic wave-arrival counter

    const int tid  = threadIdx.x;
    const int bi   = blockIdx.x;
    // XCD-clustered mapping: rg lives on an XCD pair (assumes xcd ~ bi&7;
    // wrong assumption -> random placement, correctness unaffected).
    const int rg   = (bi & 7) >> 1;               // row-group: rows [32rg, +32)
    const int cg   = ((bi >> 3) << 1) | (bi & 1); // 0..63: h-cols [16cg, +16)
    const int kq   = tid >> 6;     // wave = K-quarter
    const int lane = tid & 63;
    const int l31  = lane & 31;
    const int lhi  = lane >> 5;    // 0/1

    const int row = rg * 32 + l31;             // A row (m = lane&31)

    if (tid == 0) wcnt = 0;

    // ---- W fragments into registers, forever ----
    // wave kq covers x k-cols [kq*128,+128) and h k-cols [kq*256,+256),
    // two n-tiles (pcols cg*64 + nt*32 + l31).
    short8 wb[48];   // [x j=0..7 | h j=0..15] x 2 n-tiles
    const unsigned short* wb0 = Wp + (size_t)(cg * 64 + l31) * KTOT + lhi * 8;
    const unsigned short* wb1 = wb0 + (size_t)32 * KTOT;
    #pragma unroll
    for (int j = 0; j < 8; ++j) {
        int k = (kq * 8 + j) * 16;
        wb[2 * j]     = *(const short8*)(wb0 + k);
        wb[2 * j + 1] = *(const short8*)(wb1 + k);
    }
    #pragma unroll
    for (int j = 0; j < 16; ++j) {
        int k = 512 + (kq * 16 + j) * 16;
        wb[16 + 2 * j]     = *(const short8*)(wb0 + k);
        wb[16 + 2 * j + 1] = *(const short8*)(wb1 + k);
    }

    // ---- gate ownership: thread -> (row r, cols 2cp, 2cp+1) ----
    const int gr = tid & 31;       // gate row 0..31
    const int cp = tid >> 5;       // col-pair 0..7
    float bi_[2], bj_[2], bf_[2], bo_[2];
    #pragma unroll
    for (int u = 0; u < 2; ++u) {
        int hcg = cg * 16 + cp * 2 + u;
        bi_[u] = bk[hcg];
        bj_[u] = bk[H + hcg];
        bf_[u] = bk[2 * H + hcg] + 1.0f;  // forget bias folded
        bo_[u] = bk[3 * H + hcg];
    }
    float cs0 = 0.f, cs1 = 0.f;   // cell state for (gr, 2cp) / (gr, 2cp+1)

    // consumer wave kq depends on producer blocks cg' in [16kq, 16kq+16)
    const unsigned int* const fpoll = arr + (rg << 6) + (kq << 4) + (lane & 15);
    unsigned int* const fmine = arr + (rg << 6) + cg;
    const unsigned short* const xbase = xb + (size_t)row * D + kq * 128 + lhi * 8;
    // consumer fragment base within a slab (add (t-1)*HSTRIDE per step)
    const size_t hoff = (size_t)row * H + kq * 256 + lhi * 8;

    const f32x16 fz = {0.f,0.f,0.f,0.f,0.f,0.f,0.f,0.f,
                       0.f,0.f,0.f,0.f,0.f,0.f,0.f,0.f};

    __syncthreads();   // wcnt init visible

    for (int t = 0; t < T; ++t) {
        f32x16 a00 = fz, a01 = fz, a10 = fz, a11 = fz;  // [parity][ntile]

        // ---- issue x loads first (no h dependency) ----
        const unsigned short* xr = xbase + (size_t)t * (B * D);
        short8 xv[8];
        #pragma unroll
        for (int j = 0; j < 8; ++j)
            xv[j] = *(const short8*)(xr + j * 16);

        short8 hv[16];
        const bool have_h = (t > 0);
        if (have_h) {
            // ---- pipelined hot poll of 16 block flags (one 64B line) ----
            unsigned int fa = __hip_atomic_load(fpoll, __ATOMIC_RELAXED,
                                                __HIP_MEMORY_SCOPE_AGENT);
            for (;;) {
                unsigned int fb = __hip_atomic_load(fpoll, __ATOMIC_RELAXED,
                                                    __HIP_MEMORY_SCOPE_AGENT);
                if (fa >= (unsigned)t) break;
                fa = fb;
            }
            asm volatile("" ::: "memory");

            // ---- issue h fragment loads immediately (cached; L2 dedups) ----
            const unsigned short* hp = hring + (size_t)(t - 1) * HSTRIDE + hoff;
            #pragma unroll
            for (int j = 0; j < 16; ++j)
                hv[j] = *(const short8*)(hp + j * 16);
        }

        // ---- x-MFMAs execute under the h cache-fill shadow ----
        #pragma unroll
        for (int j = 0; j < 8; ++j) {
            if (j & 1) {
                a10 = __builtin_amdgcn_mfma_f32_32x32x16_bf16(xv[j], wb[2 * j],     a10, 0, 0, 0);
                a11 = __builtin_amdgcn_mfma_f32_32x32x16_bf16(xv[j], wb[2 * j + 1], a11, 0, 0, 0);
            } else {
                a00 = __builtin_amdgcn_mfma_f32_32x32x16_bf16(xv[j], wb[2 * j],     a00, 0, 0, 0);
                a01 = __builtin_amdgcn_mfma_f32_32x32x16_bf16(xv[j], wb[2 * j + 1], a01, 0, 0, 0);
            }
        }
        if (have_h) {
            #pragma unroll
            for (int j = 0; j < 16; ++j) {
                if (j & 1) {
                    a10 = __builtin_amdgcn_mfma_f32_32x32x16_bf16(hv[j], wb[16 + 2 * j],     a10, 0, 0, 0);
                    a11 = __builtin_amdgcn_mfma_f32_32x32x16_bf16(hv[j], wb[16 + 2 * j + 1], a11, 0, 0, 0);
                } else {
                    a00 = __builtin_amdgcn_mfma_f32_32x32x16_bf16(hv[j], wb[16 + 2 * j],     a00, 0, 0, 0);
                    a01 = __builtin_amdgcn_mfma_f32_32x32x16_bf16(hv[j], wb[16 + 2 * j + 1], a01, 0, 0, 0);
                }
            }
        }

        f32x16 z0 = a00 + a10;   // ntile 0
        f32x16 z1 = a01 + a11;   // ntile 1

        // ---- K-quarter partials to dbuf'd LDS ----
        // C/D: col=lane&31, row=(reg&3)+8*(reg>>2)+4*lhi
        float (*zb)[64][36] = zbuf[t & 1];
        #pragma unroll
        for (int q = 0; q < 4; ++q) {
            float4 v0 = { z0[4 * q + 0], z0[4 * q + 1], z0[4 * q + 2], z0[4 * q + 3] };
            *(float4*)&zb[kq][l31][lhi * 4 + q * 8] = v0;
            float4 v1 = { z1[4 * q + 0], z1[4 * q + 1], z1[4 * q + 2], z1[4 * q + 3] };
            *(float4*)&zb[kq][32 + l31][lhi * 4 + q * 8] = v1;
        }
        __syncthreads();   // the ONLY barrier per step (zbuf dbuf covers reuse)

        // ---- gates: thread owns (gr, 2cp) and (gr, 2cp+1); pack 1 uint ----
        unsigned short hbf[2];
        #pragma unroll
        for (int u = 0; u < 2; ++u) {
            int pcb = (cp * 2 + u) * 4;
            float zi = zb[0][pcb + 0][gr] + zb[1][pcb + 0][gr]
                     + zb[2][pcb + 0][gr] + zb[3][pcb + 0][gr] + bi_[u];
            float zj = zb[0][pcb + 1][gr] + zb[1][pcb + 1][gr]
                     + zb[2][pcb + 1][gr] + zb[3][pcb + 1][gr] + bj_[u];
            float zf = zb[0][pcb + 2][gr] + zb[1][pcb + 2][gr]
                     + zb[2][pcb + 2][gr] + zb[3][pcb + 2][gr] + bf_[u];
            float zo = zb[0][pcb + 3][gr] + zb[1][pcb + 3][gr]
                     + zb[2][pcb + 3][gr] + zb[3][pcb + 3][gr] + bo_[u];
            float& cc = u ? cs1 : cs0;
            float cn = cc * sigm(zf) + sigm(zi) * tanh_fast(zj);
            cc = cn;
            hbf[u] = f2bf(sigm(zo) * tanh_fast(cn));
        }

        // ---- direct agent-scope store of own packed uint (no hbuf stage) ----
        {
            unsigned int v = (unsigned int)hbf[0] | ((unsigned int)hbf[1] << 16);
            unsigned int* hdst = (unsigned int*)(hring + (size_t)t * HSTRIDE);
            __hip_atomic_store(&hdst[(size_t)(rg * 32 + gr) * 512 + cg * 8 + cp], v,
                               __ATOMIC_RELAXED, __HIP_MEMORY_SCOPE_AGENT);
        }
        // per-wave drain (waits exactly this wave's 64 stores), then monotonic
        // LDS arrival; last-arriving wave publishes the block flag. No barrier.
        asm volatile("s_waitcnt vmcnt(0)" ::: "memory");
        if (lane == 0) {
            unsigned int old = __hip_atomic_fetch_add(&wcnt, 1u, __ATOMIC_RELAXED,
                                                      __HIP_MEMORY_SCOPE_WORKGROUP);
            if (old == 4u * (unsigned)t + 3u)
                __hip_atomic_store(fmine, (unsigned)(t + 1),
                                   __ATOMIC_RELAXED, __HIP_MEMORY_SCOPE_AGENT);
        }
    }
}

// out[128][1000] = h(bf16)[128][1024] @ w[1024][1000] + b
__global__ __launch_bounds__(256) void proj_kernel(
    const unsigned short* __restrict__ hb, const float* __restrict__ w,
    const float* __restrict__ bias, float* __restrict__ out)
{
    int cidx = blockIdx.x * 256 + threadIdx.x;  // 0..1023
    int bg   = blockIdx.y;                      // 0..7 -> 16 rows each
    bool valid = cidx < 1000;
    float acc[16];
    #pragma unroll
    for (int i = 0; i < 16; ++i) acc[i] = 0.f;

    for (int k = 0; k < H; k += 4) {
        float w0 = 0.f, w1 = 0.f, w2 = 0.f, w3 = 0.f;
        if (valid) {
            w0 = w[(size_t)(k + 0) * 1000 + cidx];
            w1 = w[(size_t)(k + 1) * 1000 + cidx];
            w2 = w[(size_t)(k + 2) * 1000 + cidx];
            w3 = w[(size_t)(k + 3) * 1000 + cidx];
        }
        #pragma unroll
        for (int i = 0; i < 16; ++i) {
            ushort4 hv = *(const ushort4*)&hb[(size_t)(bg * 16 + i) * H + k];
            acc[i] += bf2f(hv.x) * w0 + bf2f(hv.y) * w1
                    + bf2f(hv.z) * w2 + bf2f(hv.w) * w3;
        }
    }
    if (valid) {
        #pragma unroll
        for (int i = 0; i < 16; ++i)
            out[(size_t)(bg * 16 + i) * 1000 + cidx] = acc[i] + bias[cidx];
    }
}

extern "C" void kernel_launch(void* const* d_in, const int* in_sizes, int n_in,
                              void* d_out, int out_size, void* d_ws, size_t ws_size,
                              hipStream_t stream) {
    const float* x  = (const float*)d_in[0];  // [B,T,D]
    const float* Wk = (const float*)d_in[1];  // [D+H, 4H]
    const float* bk = (const float*)d_in[2];  // [4H]
    const float* w  = (const float*)d_in[3];  // [H, C]
    const float* b  = (const float*)d_in[4];  // [C]
    float* out = (float*)d_out;               // [B, C]

    char* p = (char*)d_ws;
    unsigned short* xb = (unsigned short*)p;  p += (size_t)B * T * D * 2;   // 33.55 MB
    unsigned short* Wp = (unsigned short*)p;  p += (size_t)N4 * KTOT * 2;   // 12.58 MB
    unsigned short* hr = (unsigned short*)p;  p += HSTRIDE * T * 2;         // 68.16 MB
    unsigned int*   ar = (unsigned int*)p;    p += 4 * 64 * 4;              // 1 KB flags

    // flags must start zeroed (ws re-poisoned 0xAA before every timed call).
    // hring needs no init: step-t slab is stored (agent-scope, through to LLC)
    // before any flag-gated cached read of it; addresses are virgin within the
    // dispatch and inter-dispatch L2 wb+inv cleans the poison.
    hipMemsetAsync(ar, 0, 4 * 64 * 4, stream);

    convert_x<<<dim3(T * B), dim3(256), 0, stream>>>(x, xb);
    convert_W<<<dim3(N4 / 32, KTOT / 32), dim3(256), 0, stream>>>(Wk, Wp);

    lstm_persist<<<dim3(256), dim3(256), 0, stream>>>(xb, Wp, bk, hr, ar);

    // final hidden state is the t=255 slab
    proj_kernel<<<dim3(4, 8), dim3(256), 0, stream>>>(hr + (size_t)(T - 1) * HSTRIDE,
                                                      w, b, out);
}

// Round 5
// 1550.936 us; speedup vs baseline: 2.1415x; 2.1415x over previous
//
#include <hip/hip_runtime.h>
#include <math.h>

// Problem constants
#define B 128
#define T 256
#define D 512
#define H 1024
#define KTOT 1536   // D + H
#define N4 4096     // 4*H

// h ring: one slab per step, 4KB skew. Slab layout is BLOCK-MAJOR:
// [rg*64+cg][r32][c16] — each producer block owns a dense 1KB region
// (full-line writes, no amplification; consumers read dense 1KB chunks).
#define HSTRIDE ((size_t)B * H + 2048)   // in ushorts; 266240 B per step

typedef short short8 __attribute__((ext_vector_type(8)));
typedef float f32x16 __attribute__((ext_vector_type(16)));

__device__ __forceinline__ unsigned short f2bf(float f) {
    unsigned int u = __builtin_bit_cast(unsigned int, f);
    unsigned int r = (u + 0x7fffu + ((u >> 16) & 1u)) >> 16;  // RNE
    return (unsigned short)r;
}
__device__ __forceinline__ float bf2f(unsigned short s) {
    unsigned int u = ((unsigned int)s) << 16;
    return __builtin_bit_cast(float, u);
}
__device__ __forceinline__ float sigm(float x) { return 1.f / (1.f + __expf(-x)); }
__device__ __forceinline__ float tanh_fast(float x) {
    return 1.f - 2.f / (1.f + __expf(2.f * x));
}

// x fp32 [B][T][D] -> xb bf16 [T][B][D]
__global__ __launch_bounds__(256) void convert_x(
    const float* __restrict__ x, unsigned short* __restrict__ xb)
{
    int bid = blockIdx.x;          // t*B + b
    int t = bid >> 7;
    int b = bid & 127;
    int d = threadIdx.x * 2;
    const float2 v = *(const float2*)&x[((size_t)b * T + t) * D + d];
    unsigned int packed = (unsigned int)f2bf(v.x) | ((unsigned int)f2bf(v.y) << 16);
    *(unsigned int*)&xb[((size_t)t * B + b) * D + d] = packed;
}

// Wk fp32 [KTOT][4H] -> Wp bf16 [4096][KTOT], permuted: pcol = hc*4 + g
__global__ __launch_bounds__(256) void convert_W(
    const float* __restrict__ Wk, unsigned short* __restrict__ Wp)
{
    __shared__ float tile[32][33];
    int nb = blockIdx.x;   // 0..127
    int kb = blockIdx.y;   // 0..47
    int tx = threadIdx.x & 31;
    int ty = threadIdx.x >> 5;   // 0..7
    #pragma unroll
    for (int i = 0; i < 4; ++i) {
        int k = kb * 32 + ty + i * 8;
        tile[ty + i * 8][tx] = Wk[(size_t)k * N4 + nb * 32 + tx];
    }
    __syncthreads();
    #pragma unroll
    for (int i = 0; i < 4; ++i) {
        int n = nb * 32 + ty + i * 8;
        int pcol = ((n & 1023) << 2) | (n >> 10);
        Wp[(size_t)pcol * KTOT + kb * 32 + tx] = f2bf(tile[tx][ty + i * 8]);
    }
}

// Persistent LSTM. 256 blocks x 256 threads, 1 block/CU, W in registers.
// Round-3 structure (hbuf staging, 2 barriers, per-wave drain + block flag)
// + XCD-clustered rg/cg remap (FETCH -270MB evidence, r4)
// + block-major h slab (dense 1KB stores/loads, zero write amplification).
__global__ __launch_bounds__(256, 1) void lstm_persist(
    const unsigned short* __restrict__ xb,     // [T][B][D] bf16
    const unsigned short* __restrict__ Wp,     // [4096][KTOT] bf16 permuted
    const float* __restrict__ bk,              // [4H]
    unsigned short* __restrict__ hring,        // [T][HSTRIDE] bf16 ring, block-major
    unsigned int* __restrict__ arr)            // [4 rg][64 cg] block flags (zeroed)
{
    __shared__ float zbuf[4][64][36];              // K-quarter partials, 36864 B
    __shared__ unsigned short hbuf[32][20];        // 1280 B
    __shared__ unsigned int wcnt;                  // monotonic wave-arrival counter

    const int tid  = threadIdx.x;
    const int bi   = blockIdx.x;
    // XCD-clustered mapping: rg lives on an XCD pair (assumes xcd ~ bi&7;
    // wrong assumption -> random placement, correctness unaffected).
    const int rg   = (bi & 7) >> 1;               // row-group: rows [32rg, +32)
    const int cg   = ((bi >> 3) << 1) | (bi & 1); // 0..63: h-cols [16cg, +16)
    const int kq   = tid >> 6;     // wave = K-quarter
    const int lane = tid & 63;
    const int l31  = lane & 31;
    const int lhi  = lane >> 5;    // 0/1

    const int row = rg * 32 + l31;             // A row (m = lane&31)

    if (tid == 0) wcnt = 0;

    // ---- W fragments into registers, forever ----
    // wave kq covers x k-cols [kq*128,+128) and h k-cols [kq*256,+256),
    // two n-tiles (pcols cg*64 + nt*32 + l31).
    short8 wb[48];   // [x j=0..7 | h j=0..15] x 2 n-tiles
    const unsigned short* wb0 = Wp + (size_t)(cg * 64 + l31) * KTOT + lhi * 8;
    const unsigned short* wb1 = wb0 + (size_t)32 * KTOT;
    #pragma unroll
    for (int j = 0; j < 8; ++j) {
        int k = (kq * 8 + j) * 16;
        wb[2 * j]     = *(const short8*)(wb0 + k);
        wb[2 * j + 1] = *(const short8*)(wb1 + k);
    }
    #pragma unroll
    for (int j = 0; j < 16; ++j) {
        int k = 512 + (kq * 16 + j) * 16;
        wb[16 + 2 * j]     = *(const short8*)(wb0 + k);
        wb[16 + 2 * j + 1] = *(const short8*)(wb1 + k);
    }

    // ---- bias preload for this thread's two gate elements (round-3 map) ----
    float bi_[2], bj_[2], bf_[2], bo_[2];
    #pragma unroll
    for (int u = 0; u < 2; ++u) {
        int e   = tid + u * 256;
        int hcl = e >> 5;                 // 0..15
        int hcg = cg * 16 + hcl;
        bi_[u] = bk[hcg];
        bj_[u] = bk[H + hcg];
        bf_[u] = bk[2 * H + hcg] + 1.0f;  // forget bias folded
        bo_[u] = bk[3 * H + hcg];
    }
    float cs0 = 0.f, cs1 = 0.f;   // cell state, persistent in registers

    // consumer wave kq depends on producer blocks cg' in [16kq, 16kq+16)
    const unsigned int* const fpoll = arr + (rg << 6) + (kq << 4) + (lane & 15);
    unsigned int* const fmine = arr + (rg << 6) + cg;
    const unsigned short* const xbase = xb + (size_t)row * D + kq * 128 + lhi * 8;
    // consumer chunk-j base within a slab: producer block (rg, kq*16+j)'s
    // dense region + this lane's (r32=l31, c16=lhi*8) fragment.
    const size_t hoff = (size_t)(rg * 64 + kq * 16) * 512 + l31 * 16 + lhi * 8;
    // producer store base (uint index): dense 1KB region, offset = tid
    const size_t soff = (size_t)(rg * 64 + cg) * 256;

    const f32x16 fz = {0.f,0.f,0.f,0.f,0.f,0.f,0.f,0.f,
                       0.f,0.f,0.f,0.f,0.f,0.f,0.f,0.f};

    __syncthreads();   // wcnt init visible

    for (int t = 0; t < T; ++t) {
        f32x16 a00 = fz, a01 = fz, a10 = fz, a11 = fz;  // [parity][ntile]

        // ---- issue x loads first (no h dependency; fill under poll shadow) ----
        const unsigned short* xr = xbase + (size_t)t * (B * D);
        short8 xv[8];
        #pragma unroll
        for (int j = 0; j < 8; ++j)
            xv[j] = *(const short8*)(xr + j * 16);

        short8 hv[16];
        const bool have_h = (t > 0);
        if (have_h) {
            // ---- per-wave poll of 16 block flags (one 64B line), backoff spin
            while (__hip_atomic_load(fpoll, __ATOMIC_RELAXED,
                                     __HIP_MEMORY_SCOPE_AGENT) < (unsigned)t)
                __builtin_amdgcn_s_sleep(1);
            asm volatile("" ::: "memory");

            // ---- h fragment loads: 16 dense 1KB chunks (fully coalesced;
            // first toucher per XCD fills L2 from LLC, siblings hit L2)
            const unsigned short* hp = hring + (size_t)(t - 1) * HSTRIDE + hoff;
            #pragma unroll
            for (int j = 0; j < 16; ++j)
                hv[j] = *(const short8*)(hp + j * 512);
        }

        // ---- x-MFMAs execute under the h cache-fill shadow ----
        #pragma unroll
        for (int j = 0; j < 8; ++j) {
            if (j & 1) {
                a10 = __builtin_amdgcn_mfma_f32_32x32x16_bf16(xv[j], wb[2 * j],     a10, 0, 0, 0);
                a11 = __builtin_amdgcn_mfma_f32_32x32x16_bf16(xv[j], wb[2 * j + 1], a11, 0, 0, 0);
            } else {
                a00 = __builtin_amdgcn_mfma_f32_32x32x16_bf16(xv[j], wb[2 * j],     a00, 0, 0, 0);
                a01 = __builtin_amdgcn_mfma_f32_32x32x16_bf16(xv[j], wb[2 * j + 1], a01, 0, 0, 0);
            }
        }
        if (have_h) {
            #pragma unroll
            for (int j = 0; j < 16; ++j) {
                if (j & 1) {
                    a10 = __builtin_amdgcn_mfma_f32_32x32x16_bf16(hv[j], wb[16 + 2 * j],     a10, 0, 0, 0);
                    a11 = __builtin_amdgcn_mfma_f32_32x32x16_bf16(hv[j], wb[16 + 2 * j + 1], a11, 0, 0, 0);
                } else {
                    a00 = __builtin_amdgcn_mfma_f32_32x32x16_bf16(hv[j], wb[16 + 2 * j],     a00, 0, 0, 0);
                    a01 = __builtin_amdgcn_mfma_f32_32x32x16_bf16(hv[j], wb[16 + 2 * j + 1], a01, 0, 0, 0);
                }
            }
        }

        f32x16 z0 = a00 + a10;   // ntile 0
        f32x16 z1 = a01 + a11;   // ntile 1

        // ---- K-quarter partials to LDS. C/D: col=lane&31, row=(reg&3)+8*(reg>>2)+4*lhi
        #pragma unroll
        for (int q = 0; q < 4; ++q) {
            float4 v0 = { z0[4 * q + 0], z0[4 * q + 1], z0[4 * q + 2], z0[4 * q + 3] };
            *(float4*)&zbuf[kq][l31][lhi * 4 + q * 8] = v0;
            float4 v1 = { z1[4 * q + 0], z1[4 * q + 1], z1[4 * q + 2], z1[4 * q + 3] };
            *(float4*)&zbuf[kq][32 + l31][lhi * 4 + q * 8] = v1;
        }
        __syncthreads();   // zbuf complete (also fences hbuf(t-1) reads vs writes)

        // ---- gates: 512 h-elems/block, 2 per thread; results to hbuf (LDS) ----
        #pragma unroll
        for (int u = 0; u < 2; ++u) {
            int e   = tid + u * 256;
            int r   = e & 31;
            int hcl = e >> 5;
            int pcb = hcl * 4;
            float zi = zbuf[0][pcb + 0][r] + zbuf[1][pcb + 0][r]
                     + zbuf[2][pcb + 0][r] + zbuf[3][pcb + 0][r] + bi_[u];
            float zj = zbuf[0][pcb + 1][r] + zbuf[1][pcb + 1][r]
                     + zbuf[2][pcb + 1][r] + zbuf[3][pcb + 1][r] + bj_[u];
            float zf = zbuf[0][pcb + 2][r] + zbuf[1][pcb + 2][r]
                     + zbuf[2][pcb + 2][r] + zbuf[3][pcb + 2][r] + bf_[u];
            float zo = zbuf[0][pcb + 3][r] + zbuf[1][pcb + 3][r]
                     + zbuf[2][pcb + 3][r] + zbuf[3][pcb + 3][r] + bo_[u];
            float& cc = u ? cs1 : cs0;
            float cn = cc * sigm(zf) + sigm(zi) * tanh_fast(zj);
            cc = cn;
            float hn = sigm(zo) * tanh_fast(cn);
            hbuf[r][hcl] = f2bf(hn);
        }
        __syncthreads();   // hbuf complete (also fences zbuf(t) reads vs t+1 writes)

        // ---- dense h-store: 256 consecutive uints (1KB region, full lines) ----
        {
            int r  = tid >> 3;
            int cp = tid & 7;
            unsigned int v = *(const unsigned int*)&hbuf[r][cp * 2];
            unsigned int* hdst = (unsigned int*)(hring + (size_t)t * HSTRIDE);
            __hip_atomic_store(&hdst[soff + tid], v,
                               __ATOMIC_RELAXED, __HIP_MEMORY_SCOPE_AGENT);
        }
        // per-wave drain (4 full lines), then monotonic LDS arrival;
        // last-arriving wave publishes the block flag. No barrier.
        asm volatile("s_waitcnt vmcnt(0)" ::: "memory");
        if (lane == 0) {
            unsigned int old = __hip_atomic_fetch_add(&wcnt, 1u, __ATOMIC_RELAXED,
                                                      __HIP_MEMORY_SCOPE_WORKGROUP);
            if (old == 4u * (unsigned)t + 3u)
                __hip_atomic_store(fmine, (unsigned)(t + 1),
                                   __ATOMIC_RELAXED, __HIP_MEMORY_SCOPE_AGENT);
        }
    }
}

// out[128][1000] = h(bf16, block-major slab)[128][1024] @ w[1024][1000] + b
__global__ __launch_bounds__(256) void proj_kernel(
    const unsigned short* __restrict__ hb, const float* __restrict__ w,
    const float* __restrict__ bias, float* __restrict__ out)
{
    int cidx = blockIdx.x * 256 + threadIdx.x;  // 0..1023
    int bg   = blockIdx.y;                      // 0..7 -> 16 rows each
    bool valid = cidx < 1000;
    float acc[16];
    #pragma unroll
    for (int i = 0; i < 16; ++i) acc[i] = 0.f;

    for (int k = 0; k < H; k += 4) {
        float w0 = 0.f, w1 = 0.f, w2 = 0.f, w3 = 0.f;
        if (valid) {
            w0 = w[(size_t)(k + 0) * 1000 + cidx];
            w1 = w[(size_t)(k + 1) * 1000 + cidx];
            w2 = w[(size_t)(k + 2) * 1000 + cidx];
            w3 = w[(size_t)(k + 3) * 1000 + cidx];
        }
        #pragma unroll
        for (int i = 0; i < 16; ++i) {
            int row = bg * 16 + i;
            // block-major: [ (row>>5)*64 + (k>>4) ][ row&31 ][ k&15 ]
            size_t a = (size_t)((row >> 5) * 64 + (k >> 4)) * 512
                     + (size_t)(row & 31) * 16 + (k & 15);
            ushort4 hv = *(const ushort4*)&hb[a];
            acc[i] += bf2f(hv.x) * w0 + bf2f(hv.y) * w1
                    + bf2f(hv.z) * w2 + bf2f(hv.w) * w3;
        }
    }
    if (valid) {
        #pragma unroll
        for (int i = 0; i < 16; ++i)
            out[(size_t)(bg * 16 + i) * 1000 + cidx] = acc[i] + bias[cidx];
    }
}

extern "C" void kernel_launch(void* const* d_in, const int* in_sizes, int n_in,
                              void* d_out, int out_size, void* d_ws, size_t ws_size,
                              hipStream_t stream) {
    const float* x  = (const float*)d_in[0];  // [B,T,D]
    const float* Wk = (const float*)d_in[1];  // [D+H, 4H]
    const float* bk = (const float*)d_in[2];  // [4H]
    const float* w  = (const float*)d_in[3];  // [H, C]
    const float* b  = (const float*)d_in[4];  // [C]
    float* out = (float*)d_out;               // [B, C]

    char* p = (char*)d_ws;
    unsigned short* xb = (unsigned short*)p;  p += (size_t)B * T * D * 2;   // 33.55 MB
    unsigned short* Wp = (unsigned short*)p;  p += (size_t)N4 * KTOT * 2;   // 12.58 MB
    unsigned short* hr = (unsigned short*)p;  p += HSTRIDE * T * 2;         // 68.16 MB
    unsigned int*   ar = (unsigned int*)p;    p += 4 * 64 * 4;              // 1 KB flags

    // flags must start zeroed (ws re-poisoned 0xAA before every timed call).
    // hring needs no init: step-t slab is stored (agent-scope, through to LLC)
    // before any flag-gated cached read of it; addresses are virgin within the
    // dispatch and inter-dispatch L2 wb+inv cleans the poison.
    hipMemsetAsync(ar, 0, 4 * 64 * 4, stream);

    convert_x<<<dim3(T * B), dim3(256), 0, stream>>>(x, xb);
    convert_W<<<dim3(N4 / 32, KTOT / 32), dim3(256), 0, stream>>>(Wk, Wp);

    lstm_persist<<<dim3(256), dim3(256), 0, stream>>>(xb, Wp, bk, hr, ar);

    // final hidden state is the t=255 slab (block-major layout)
    proj_kernel<<<dim3(4, 8), dim3(256), 0, stream>>>(hr + (size_t)(T - 1) * HSTRIDE,
                                                      w, b, out);
}